// Round 8
// baseline (858.330 us; speedup 1.0000x reference)
//
#include <hip/hip_runtime.h>

#define S_LEN 512
#define BATCH 256
#define EMB   300
#define HID   256
#define VOCAB 50257
#define NPROD 786
#define NLOG2E -1.44269504089f

#define EW_BYTES   51463168ull          // 50257*256*4 (f32, pre-scaled by -log2e)
#define ASEQ_BYTES 67108864ull          // 512*256*256*2 (f16)

typedef __attribute__((ext_vector_type(8))) _Float16 f16x8;
typedef __attribute__((ext_vector_type(4))) _Float16 f16x4;
typedef __attribute__((ext_vector_type(2))) __fp16   fp16v2;
typedef __attribute__((ext_vector_type(4))) float    f32x4;

// Barrier waiting only lgkmcnt(0): LDS ordered, global loads stay in flight.
__device__ __forceinline__ void block_sync_lds() {
    asm volatile("" ::: "memory");
    __builtin_amdgcn_s_waitcnt(0xC07F);   // vmcnt=63, expcnt=7, lgkmcnt=0
    __builtin_amdgcn_s_barrier();
    asm volatile("" ::: "memory");
}

__device__ __forceinline__ float sigmoid_scaled(float xs) {   // xs = -log2e * x
    float e = __builtin_amdgcn_exp2f(xs);
    return __builtin_amdgcn_rcpf(1.0f + e);
}

// ---------------------------------------------------------------------------
// Producer: EW[v][j] = -log2e * (emb[v] @ Wi)[j], f32. (unchanged from R7)
// ---------------------------------------------------------------------------
__global__ __launch_bounds__(256, 1)
void k_embwi(const float* __restrict__ emb, const float* __restrict__ Wi,
             float* __restrict__ EW) {
    const int tid  = threadIdx.x;
    const int wv   = tid >> 6;
    const int lane = tid & 63;
    const int ln   = lane & 15;
    const int q    = lane >> 4;
    const int m0   = blockIdx.x * 64;

    f16x8 bfrag[10][4];
#pragma unroll
    for (int kc = 0; kc < 10; kc++) {
#pragma unroll
        for (int nt = 0; nt < 4; nt++) {
            const int n = wv * 64 + nt * 16 + ln;
            f16x8 u;
#pragma unroll
            for (int j = 0; j < 8; j++) {
                const int k = kc * 32 + q * 8 + j;
                u[j] = (k < EMB) ? (_Float16)(Wi[k * HID + n] * NLOG2E) : (_Float16)0.f;
            }
            bfrag[kc][nt] = u;
        }
    }

    const float* arow[4];
#pragma unroll
    for (int mt = 0; mt < 4; mt++) {
        int row = m0 + mt * 16 + ln; if (row >= VOCAB) row = VOCAB - 1;
        arow[mt] = emb + (long)row * EMB + q * 8;
    }

    auto load_af = [&](int kc, int mt) -> f16x8 {
        const float* p = arow[mt] + kc * 32;
        f16x8 v;
        if (kc < 9 || q == 0) {
            f32x4 a = *(const f32x4*)p;
            f32x4 b = *(const f32x4*)(p + 4);
#pragma unroll
            for (int r = 0; r < 4; r++) { v[r] = (_Float16)a[r]; v[4 + r] = (_Float16)b[r]; }
        } else if (q == 1) {
            f32x4 a = *(const f32x4*)p;
#pragma unroll
            for (int r = 0; r < 4; r++) { v[r] = (_Float16)a[r]; v[4 + r] = (_Float16)0.f; }
        } else {
#pragma unroll
            for (int r = 0; r < 8; r++) v[r] = (_Float16)0.f;
        }
        return v;
    };

    f32x4 acc[4][4];
#pragma unroll
    for (int mt = 0; mt < 4; mt++)
#pragma unroll
        for (int nt = 0; nt < 4; nt++)
            acc[mt][nt] = f32x4{0.f, 0.f, 0.f, 0.f};

    f16x8 af[4], afn[4];
#pragma unroll
    for (int mt = 0; mt < 4; mt++) af[mt] = load_af(0, mt);

#pragma unroll
    for (int kc = 0; kc < 10; kc++) {
        if (kc < 9) {
#pragma unroll
            for (int mt = 0; mt < 4; mt++) afn[mt] = load_af(kc + 1, mt);
        }
#pragma unroll
        for (int mt = 0; mt < 4; mt++)
#pragma unroll
            for (int nt = 0; nt < 4; nt++)
                acc[mt][nt] = __builtin_amdgcn_mfma_f32_16x16x32_f16(
                    af[mt], bfrag[kc][nt], acc[mt][nt], 0, 0, 0);
#pragma unroll
        for (int mt = 0; mt < 4; mt++) af[mt] = afn[mt];
    }

#pragma unroll
    for (int mt = 0; mt < 4; mt++)
#pragma unroll
        for (int nt = 0; nt < 4; nt++) {
            const int col = wv * 64 + nt * 16 + ln;
#pragma unroll
            for (int r = 0; r < 4; r++) {
                const int mm = m0 + mt * 16 + q * 4 + r;
                if (mm < VOCAB) EW[(long)mm * HID + col] = acc[mt][nt][r];
            }
        }
}

// ---------------------------------------------------------------------------
// Expand: A_seq[t][b][j] = (f16) EW[words[b,t]][j]. (unchanged from R7)
// ---------------------------------------------------------------------------
__global__ __launch_bounds__(256)
void k_expand(const int* __restrict__ words, const float* __restrict__ EW,
              _Float16* __restrict__ As) {
    const int g  = blockIdx.x * 256 + threadIdx.x;
    const int e0 = g << 3;
    const int t  = e0 >> 16;
    const int b  = (e0 >> 8) & 255;
    const int j0 = e0 & 255;
    const float* src = EW + ((long)words[b * S_LEN + t] << 8) + j0;
    f32x4 a = *(const f32x4*)src;
    f32x4 c = *(const f32x4*)(src + 4);
    f16x8 v;
#pragma unroll
    for (int r = 0; r < 4; r++) { v[r] = (_Float16)a[r]; v[4 + r] = (_Float16)c[r]; }
    *(f16x8*)(As + e0) = v;
}

// ---------------------------------------------------------------------------
// Consumer: SOFTWARE-PIPELINED recurrence. 16 blocks x 16 rows as TWO
// independent 8-row groups (A=rows 0-7, B=rows 8-15) skewed half a step:
//   barrier1 -> issue ds_reads(B,t) -> compute A(t) -> barrier2
//            -> issue ds_reads(A,t+1) -> compute B(t)
// Each group's LDS latency + MFMA/sigmoid dependency stalls hide under the
// other group's compute. Lanes ln>=8 broadcast-read lanes ln-8's LDS
// addresses (free) -> MFMA cols 8-15 are duplicates, never written.
// ---------------------------------------------------------------------------
#define HSTR 264
#define GB   (8 * HSTR)    // one 8-row h buffer

__global__ __launch_bounds__(256, 1)
void k_recur_p(const float* __restrict__ Wh, const _Float16* __restrict__ As,
               const float* __restrict__ fcw, const float* __restrict__ fcb,
               float* __restrict__ out) {
    __shared__ __attribute__((aligned(16))) _Float16 hA[2 * GB];
    __shared__ __attribute__((aligned(16))) _Float16 hB[2 * GB];
    __shared__ float red[256];

    const int tid  = threadIdx.x;
    const int wv   = tid >> 6;
    const int lane = tid & 63;
    const int ln   = lane & 15;
    const int lnn  = ln & 7;          // broadcast row for reads
    const int q    = lane >> 4;
    const int b0   = blockIdx.x * 16;

    // Wh^T frags (scaled by -log2e): A'[m=j][k] = Wh[k][j], j = wv*64 + mt*16 + ln
    f16x8 whf[8][4];
#pragma unroll
    for (int kc = 0; kc < 8; kc++) {
#pragma unroll
        for (int mt = 0; mt < 4; mt++) {
            const int j = wv * 64 + mt * 16 + ln;
            f16x8 u;
#pragma unroll
            for (int jj = 0; jj < 8; jj++)
                u[jj] = (_Float16)(Wh[(kc * 32 + q * 8 + jj) * HID + j] * NLOG2E);
            whf[kc][mt] = u;
        }
    }

    for (int i = tid; i < 2 * GB; i += 256) { hA[i] = (_Float16)0.f; hB[i] = (_Float16)0.f; }
    __syncthreads();

    const int jbase = wv * 64 + q * 4;   // + mt*16
    const _Float16* abaseA = As + (long)(b0 + lnn) * HID + jbase;
    const _Float16* abaseB = abaseA + 8 * HID;
    f16x4 abufA[4], abufB[4];
#pragma unroll
    for (int mt = 0; mt < 4; mt++) abufA[mt] = *(const f16x4*)(abaseA + mt * 16);
#pragma unroll
    for (int mt = 0; mt < 4; mt++) abufB[mt] = *(const f16x4*)(abaseB + mt * 16);

    const int wroff = lnn * HSTR + q * 8;            // read offset within buffer
    const int wwoff = ln * HSTR + wv * 64 + q * 4;   // write offset (ln<8 only)

    // COMPUTE(group): MFMA from hf + preact, sigmoid, write to buf[(t+1)&1]
#define COMPUTE(HF, ABUF, ABASE, BUF, T)                                                \
    {                                                                                   \
        f32x4 acc_a[4], acc_b[4];                                                       \
        _Pragma("unroll")                                                               \
        for (int mt = 0; mt < 4; mt++) {                                                \
            f16x4 av = ABUF[mt];                                                        \
            acc_a[mt] = f32x4{(float)av[0], (float)av[1], (float)av[2], (float)av[3]};  \
            acc_b[mt] = f32x4{0.f, 0.f, 0.f, 0.f};                                      \
        }                                                                               \
        const long tp = ((T) + 1 > 511) ? 511 : ((T) + 1);                              \
        _Pragma("unroll")                                                               \
        for (int mt = 0; mt < 4; mt++)                                                  \
            ABUF[mt] = *(const f16x4*)(ABASE + tp * 65536 + mt * 16);                   \
        _Pragma("unroll")                                                               \
        for (int r = 0; r < 4; r++) {               /* 8 chains, depth 4 */             \
            _Pragma("unroll")                                                           \
            for (int mt = 0; mt < 4; mt++)                                              \
                acc_a[mt] = __builtin_amdgcn_mfma_f32_16x16x32_f16(                     \
                    whf[r][mt], HF[r], acc_a[mt], 0, 0, 0);                             \
            _Pragma("unroll")                                                           \
            for (int mt = 0; mt < 4; mt++)                                              \
                acc_b[mt] = __builtin_amdgcn_mfma_f32_16x16x32_f16(                     \
                    whf[r + 4][mt], HF[r + 4], acc_b[mt], 0, 0, 0);                     \
        }                                                                               \
        _Float16* hw = BUF + (((T) + 1) & 1) * GB;                                      \
        _Pragma("unroll")                                                               \
        for (int mt = 0; mt < 4; mt++) {                                                \
            f32x4 s = acc_a[mt] + acc_b[mt];                                            \
            float r0 = sigmoid_scaled(s[0]), r1 = sigmoid_scaled(s[1]);                 \
            float r2 = sigmoid_scaled(s[2]), r3 = sigmoid_scaled(s[3]);                 \
            union { fp16v2 h2[2]; f16x4 v4; } hp;                                       \
            hp.h2[0] = __builtin_amdgcn_cvt_pkrtz(r0, r1);                              \
            hp.h2[1] = __builtin_amdgcn_cvt_pkrtz(r2, r3);                              \
            if (ln < 8) *(f16x4*)(hw + wwoff + mt * 16) = hp.v4;                        \
        }                                                                               \
    }

#define READF(HF, BUF, T)                                                               \
    {                                                                                   \
        const _Float16* hr = BUF + ((T) & 1) * GB;                                      \
        _Pragma("unroll")                                                               \
        for (int kc = 0; kc < 8; kc++)                                                  \
            HF[kc] = *(const f16x8*)(hr + wroff + kc * 32);                             \
    }

    f16x8 hfA[8], hfB[8];
    READF(hfA, hA, 0)                 // prime group A, t=0

    for (int t = 0; t < S_LEN; t++) {
        block_sync_lds();             // write_B(t-1) visible
        READF(hfB, hB, t)             // latency hides under compute A
        COMPUTE(hfA, abufA, abaseA, hA, t)
        block_sync_lds();             // write_A(t) + read_B(t) drained
        READF(hfA, hA, t + 1)         // latency hides under compute B
        COMPUTE(hfB, abufB, abaseB, hB, t)
    }
#undef COMPUTE
#undef READF

    __syncthreads();
    // final h: write(511) landed in ping buffer 0 of each group
    const _Float16* fA = hA;
    const _Float16* fB = hB;

    {   // hidden -> out[256 + (b0+row)*256 + j]
        const int row = tid >> 4, j0 = (tid & 15) * 16;
        const _Float16* src = (row < 8) ? (fA + row * HSTR + j0) : (fB + (row - 8) * HSTR + j0);
        float* dst = out + 256 + (long)(b0 + row) * HID + j0;
#pragma unroll
        for (int v = 0; v < 16; v += 4) {
            f32x4 w;
#pragma unroll
            for (int r = 0; r < 4; r++) w[r] = (float)src[v + r];
            *(f32x4*)(dst + v) = w;
        }
    }

    {   // sig head
        const int bl = tid >> 4, part = tid & 15;
        const _Float16* src = (bl < 8) ? (fA + bl * HSTR) : (fB + (bl - 8) * HSTR);
        float s = 0.f;
#pragma unroll
        for (int jj = 0; jj < 16; jj++) {
            const int j = part * 16 + jj;
            s += (float)src[j] * fcw[j];
        }
        red[bl * 16 + part] = s;
    }
    __syncthreads();
    if (tid < 16) {
        float s = fcb[0];
#pragma unroll
        for (int p = 0; p < 16; p++) s += red[tid * 16 + p];
        s *= NLOG2E;
        out[b0 + tid] = sigmoid_scaled(s);
    }
}

// ---------------------------------------------------------------------------
// Gather fallback (only if ws too small) — R5 structure, known-correct.
// ---------------------------------------------------------------------------
#define HB16 (16 * HSTR)
#define WSTR 516

__global__ __launch_bounds__(256, 1)
void k_recur_g(const float* __restrict__ Wh, const float* __restrict__ EW,
               const int* __restrict__ words,
               const float* __restrict__ fcw, const float* __restrict__ fcb,
               float* __restrict__ out) {
    __shared__ __attribute__((aligned(16))) _Float16 hbuf[2 * HB16];
    __shared__ int wtab[16 * WSTR];
    __shared__ float red[256];

    const int tid  = threadIdx.x;
    const int wv   = tid >> 6;
    const int lane = tid & 63;
    const int ln   = lane & 15;
    const int q    = lane >> 4;
    const int b0   = blockIdx.x * 16;

    for (int i = tid; i < 16 * S_LEN; i += 256)
        wtab[(i >> 9) * WSTR + (i & 511)] = words[b0 * S_LEN + i] << 10;

    f16x8 whf[8][4];
#pragma unroll
    for (int kc = 0; kc < 8; kc++) {
#pragma unroll
        for (int mt = 0; mt < 4; mt++) {
            const int j = wv * 64 + mt * 16 + ln;
            f16x8 u;
#pragma unroll
            for (int jj = 0; jj < 8; jj++)
                u[jj] = (_Float16)(Wh[(kc * 32 + q * 8 + jj) * HID + j] * NLOG2E);
            whf[kc][mt] = u;
        }
    }

    for (int i = tid; i < 2 * HB16; i += 256) hbuf[i] = (_Float16)0.f;
    __syncthreads();

    const int jbase = wv * 64 + q * 4;
    f32x4 abuf0[4], abuf1[4];
    {
        const float* r0 = (const float*)((const char*)EW + wtab[ln * WSTR + 0]) + jbase;
        const float* r1 = (const float*)((const char*)EW + wtab[ln * WSTR + 1]) + jbase;
#pragma unroll
        for (int mt = 0; mt < 4; mt++) abuf0[mt] = *(const f32x4*)(r0 + mt * 16);
#pragma unroll
        for (int mt = 0; mt < 4; mt++) abuf1[mt] = *(const f32x4*)(r1 + mt * 16);
    }

#define STEP(T, ABUF)                                                                   \
    {                                                                                   \
        const int tt = (T);                                                             \
        const _Float16* hr = hbuf + ((tt & 1) ? HB16 : 0);                              \
        _Float16*       hw = hbuf + ((tt & 1) ? 0 : HB16);                              \
        const int t2 = (tt + 2 > 511) ? 511 : (tt + 2);                                 \
        const int wofs = wtab[ln * WSTR + t2];                                          \
        f16x8 hf[8];                                                                    \
        _Pragma("unroll")                                                               \
        for (int kc = 0; kc < 8; kc++)                                                  \
            hf[kc] = *(const f16x8*)(hr + ln * HSTR + kc * 32 + q * 8);                 \
        const float* rp = (const float*)((const char*)EW + wofs) + jbase;               \
        f32x4 acc_a[4], acc_b[4];                                                       \
        _Pragma("unroll")                                                               \
        for (int mt = 0; mt < 4; mt++) { acc_a[mt] = ABUF[mt];                          \
                                         acc_b[mt] = f32x4{0.f, 0.f, 0.f, 0.f}; }      \
        _Pragma("unroll")                                                               \
        for (int mt = 0; mt < 4; mt++) ABUF[mt] = *(const f32x4*)(rp + mt * 16);        \
        _Pragma("unroll")                                                               \
        for (int r = 0; r < 4; r++) {                                                   \
            _Pragma("unroll")                                                           \
            for (int mt = 0; mt < 4; mt++)                                              \
                acc_a[mt] = __builtin_amdgcn_mfma_f32_16x16x32_f16(                     \
                    whf[r][mt], hf[r], acc_a[mt], 0, 0, 0);                             \
            _Pragma("unroll")                                                           \
            for (int mt = 0; mt < 4; mt++)                                              \
                acc_b[mt] = __builtin_amdgcn_mfma_f32_16x16x32_f16(                     \
                    whf[r + 4][mt], hf[r + 4], acc_b[mt], 0, 0, 0);                     \
        }                                                                               \
        _Pragma("unroll")                                                               \
        for (int mt = 0; mt < 4; mt++) {                                                \
            f32x4 s = acc_a[mt] + acc_b[mt];                                            \
            float r0 = sigmoid_scaled(s[0]), r1 = sigmoid_scaled(s[1]);                 \
            float r2 = sigmoid_scaled(s[2]), r3 = sigmoid_scaled(s[3]);                 \
            union { fp16v2 h2[2]; f16x4 v4; } hp;                                       \
            hp.h2[0] = __builtin_amdgcn_cvt_pkrtz(r0, r1);                              \
            hp.h2[1] = __builtin_amdgcn_cvt_pkrtz(r2, r3);                              \
            *(f16x4*)(hw + ln * HSTR + wv * 64 + mt * 16 + q * 4) = hp.v4;              \
        }                                                                               \
        block_sync_lds();                                                               \
    }

    for (int t = 0; t < S_LEN; t += 2) {
        STEP(t, abuf0);
        STEP(t + 1, abuf1);
    }
#undef STEP

    const _Float16* hf0 = hbuf;
    {
        const int row = tid >> 4, j0 = (tid & 15) * 16;
        float* dst = out + 256 + (long)(b0 + row) * HID + j0;
#pragma unroll
        for (int v = 0; v < 16; v += 4) {
            f32x4 w;
#pragma unroll
            for (int r = 0; r < 4; r++) w[r] = (float)hf0[row * HSTR + j0 + v + r];
            *(f32x4*)(dst + v) = w;
        }
    }
    {
        const int bl = tid >> 4, part = tid & 15;
        float s = 0.f;
#pragma unroll
        for (int jj = 0; jj < 16; jj++)
            s += (float)hf0[bl * HSTR + part * 16 + jj] * fcw[part * 16 + jj];
        red[bl * 16 + part] = s;
    }
    __syncthreads();
    if (tid < 16) {
        float s = fcb[0];
#pragma unroll
        for (int p = 0; p < 16; p++) s += red[tid * 16 + p];
        s *= NLOG2E;
        out[b0 + tid] = sigmoid_scaled(s);
    }
}

extern "C" void kernel_launch(void* const* d_in, const int* in_sizes, int n_in,
                              void* d_out, int out_size, void* d_ws, size_t ws_size,
                              hipStream_t stream) {
    const int*   words = (const int*)d_in[0];
    const float* emb   = (const float*)d_in[1];
    const float* Wi    = (const float*)d_in[2];
    const float* Wh    = (const float*)d_in[3];
    const float* fcw   = (const float*)d_in[4];
    const float* fcb   = (const float*)d_in[5];
    float*    EW   = (float*)d_ws;
    _Float16* As   = (_Float16*)((char*)d_ws + EW_BYTES);
    float*    outp = (float*)d_out;

    hipLaunchKernelGGL(k_embwi, dim3(NPROD), dim3(256), 0, stream, emb, Wi, EW);
    if (ws_size >= EW_BYTES + ASEQ_BYTES) {
        hipLaunchKernelGGL(k_expand, dim3(16384), dim3(256), 0, stream, words, EW, As);
        hipLaunchKernelGGL(k_recur_p, dim3(BATCH / 16), dim3(256), 0, stream,
                           Wh, As, fcw, fcb, outp);
    } else {
        hipLaunchKernelGGL(k_recur_g, dim3(BATCH / 16), dim3(256), 0, stream,
                           Wh, EW, words, fcw, fcb, outp);
    }
}

// Round 9
// 507.034 us; speedup vs baseline: 1.6928x; 1.6928x over previous
//
#include <hip/hip_runtime.h>

#define S_LEN 512
#define BATCH 256
#define EMB   300
#define HID   256
#define VOCAB 50257
#define NPROD 786
#define NLOG2E -1.44269504089f

#define EW_BYTES 25731584ull            // 50257*256*2 (f16, pre-scaled by -log2e)

typedef __attribute__((ext_vector_type(8))) _Float16 f16x8;
typedef __attribute__((ext_vector_type(4))) _Float16 f16x4;
typedef __attribute__((ext_vector_type(2))) __fp16   fp16v2;
typedef __attribute__((ext_vector_type(4))) float    f32x4;

// Barrier waiting only lgkmcnt(0): LDS ordered, global loads stay in flight.
__device__ __forceinline__ void block_sync_lds() {
    asm volatile("" ::: "memory");
    __builtin_amdgcn_s_waitcnt(0xC07F);   // vmcnt=63, expcnt=7, lgkmcnt=0
    __builtin_amdgcn_s_barrier();
    asm volatile("" ::: "memory");
}

__device__ __forceinline__ float sigmoid_scaled(float xs) {   // xs = -log2e * x
    float e = __builtin_amdgcn_exp2f(xs);
    return __builtin_amdgcn_rcpf(1.0f + e);
}

// ---------------------------------------------------------------------------
// Producer: EW[v][j] = f16( -log2e * (emb[v] @ Wi)[j] ). 786 blocks x 64 rows.
// ---------------------------------------------------------------------------
__global__ __launch_bounds__(256, 1)
void k_embwi(const float* __restrict__ emb, const float* __restrict__ Wi,
             _Float16* __restrict__ EW) {
    const int tid  = threadIdx.x;
    const int wv   = tid >> 6;
    const int lane = tid & 63;
    const int ln   = lane & 15;
    const int q    = lane >> 4;
    const int m0   = blockIdx.x * 64;

    f16x8 bfrag[10][4];
#pragma unroll
    for (int kc = 0; kc < 10; kc++) {
#pragma unroll
        for (int nt = 0; nt < 4; nt++) {
            const int n = wv * 64 + nt * 16 + ln;
            f16x8 u;
#pragma unroll
            for (int j = 0; j < 8; j++) {
                const int k = kc * 32 + q * 8 + j;
                u[j] = (k < EMB) ? (_Float16)(Wi[k * HID + n] * NLOG2E) : (_Float16)0.f;
            }
            bfrag[kc][nt] = u;
        }
    }

    const float* arow[4];
#pragma unroll
    for (int mt = 0; mt < 4; mt++) {
        int row = m0 + mt * 16 + ln; if (row >= VOCAB) row = VOCAB - 1;
        arow[mt] = emb + (long)row * EMB + q * 8;
    }

    auto load_af = [&](int kc, int mt) -> f16x8 {
        const float* p = arow[mt] + kc * 32;
        f16x8 v;
        if (kc < 9 || q == 0) {
            f32x4 a = *(const f32x4*)p;
            f32x4 b = *(const f32x4*)(p + 4);
#pragma unroll
            for (int r = 0; r < 4; r++) { v[r] = (_Float16)a[r]; v[4 + r] = (_Float16)b[r]; }
        } else if (q == 1) {
            f32x4 a = *(const f32x4*)p;
#pragma unroll
            for (int r = 0; r < 4; r++) { v[r] = (_Float16)a[r]; v[4 + r] = (_Float16)0.f; }
        } else {
#pragma unroll
            for (int r = 0; r < 8; r++) v[r] = (_Float16)0.f;
        }
        return v;
    };

    f32x4 acc[4][4];
#pragma unroll
    for (int mt = 0; mt < 4; mt++)
#pragma unroll
        for (int nt = 0; nt < 4; nt++)
            acc[mt][nt] = f32x4{0.f, 0.f, 0.f, 0.f};

    f16x8 af[4], afn[4];
#pragma unroll
    for (int mt = 0; mt < 4; mt++) af[mt] = load_af(0, mt);

#pragma unroll
    for (int kc = 0; kc < 10; kc++) {
        if (kc < 9) {
#pragma unroll
            for (int mt = 0; mt < 4; mt++) afn[mt] = load_af(kc + 1, mt);
        }
#pragma unroll
        for (int mt = 0; mt < 4; mt++)
#pragma unroll
            for (int nt = 0; nt < 4; nt++)
                acc[mt][nt] = __builtin_amdgcn_mfma_f32_16x16x32_f16(
                    af[mt], bfrag[kc][nt], acc[mt][nt], 0, 0, 0);
#pragma unroll
        for (int mt = 0; mt < 4; mt++) af[mt] = afn[mt];
    }

#pragma unroll
    for (int mt = 0; mt < 4; mt++)
#pragma unroll
        for (int nt = 0; nt < 4; nt++) {
            const int col = wv * 64 + nt * 16 + ln;
#pragma unroll
            for (int r = 0; r < 4; r++) {
                const int mm = m0 + mt * 16 + q * 4 + r;
                if (mm < VOCAB) EW[(long)mm * HID + col] = (_Float16)acc[mt][nt][r];
            }
        }
}

// ---------------------------------------------------------------------------
// Expand: A_seq[t][b][j] = EW[words[b,t]][j] (f16 -> f16 gather-copy).
// ---------------------------------------------------------------------------
__global__ __launch_bounds__(256)
void k_expand(const int* __restrict__ words, const _Float16* __restrict__ EW,
              _Float16* __restrict__ As) {
    const int g  = blockIdx.x * 256 + threadIdx.x;
    const int e0 = g << 3;
    const int t  = e0 >> 16;
    const int b  = (e0 >> 8) & 255;
    const int j0 = e0 & 255;
    const _Float16* src = EW + ((long)words[b * S_LEN + t] << 8) + j0;
    *(f16x8*)(As + e0) = *(const f16x8*)src;
}

// ---------------------------------------------------------------------------
// Consumer: recurrence with 512 threads = 8 waves = 2 waves/SIMD.
// j split 8 ways (32 cols/wave): per-wave issue halves vs R7 and the sibling
// wave on each SIMD fills dependency stalls (HW interleaves co-resident
// waves; in-order issue within a wave was R8's failure). One lgkm-only
// barrier per step; h ping-pong in LDS; A-feed streamed with depth-2
// register prefetch; k-split dual accumulator chains.
// ---------------------------------------------------------------------------
#define HSTR 264
#define HB   (16 * HSTR)

__global__ __launch_bounds__(512, 2)
void k_recur(const float* __restrict__ Wh, const _Float16* __restrict__ As,
             const float* __restrict__ fcw, const float* __restrict__ fcb,
             float* __restrict__ out) {
    __shared__ __attribute__((aligned(16))) _Float16 hbuf[2 * HB];
    __shared__ float red[512];

    const int tid  = threadIdx.x;
    const int wv   = tid >> 6;        // 0..7, j-slice of 32
    const int lane = tid & 63;
    const int ln   = lane & 15;
    const int q    = lane >> 4;
    const int b0   = blockIdx.x * 16;

    // Wh^T frags (scaled by -log2e): A'[m=j][k], j = wv*32 + mt*16 + ln, mt in {0,1}
    f16x8 whf[8][2];
#pragma unroll
    for (int kc = 0; kc < 8; kc++) {
#pragma unroll
        for (int mt = 0; mt < 2; mt++) {
            const int j = wv * 32 + mt * 16 + ln;
            f16x8 u;
#pragma unroll
            for (int jj = 0; jj < 8; jj++)
                u[jj] = (_Float16)(Wh[(kc * 32 + q * 8 + jj) * HID + j] * NLOG2E);
            whf[kc][mt] = u;
        }
    }

    for (int i = tid; i < 2 * HB; i += 512) hbuf[i] = (_Float16)0.f;
    __syncthreads();

    const int jbase = wv * 32 + q * 4;   // + mt*16
    const _Float16* abase = As + (long)(b0 + ln) * HID + jbase;
    f16x4 abuf0[2], abuf1[2];
#pragma unroll
    for (int mt = 0; mt < 2; mt++) abuf0[mt] = *(const f16x4*)(abase + 0L * 65536 + mt * 16);
#pragma unroll
    for (int mt = 0; mt < 2; mt++) abuf1[mt] = *(const f16x4*)(abase + 1L * 65536 + mt * 16);

#define STEP(T, ABUF)                                                                   \
    {                                                                                   \
        const int tt = (T);                                                             \
        const _Float16* hr = hbuf + ((tt & 1) ? HB : 0);                                \
        _Float16*       hw = hbuf + ((tt & 1) ? 0 : HB);                                \
        f16x8 hf[8];                                                                    \
        _Pragma("unroll")                                                               \
        for (int kc = 0; kc < 8; kc++)                                                  \
            hf[kc] = *(const f16x8*)(hr + ln * HSTR + kc * 32 + q * 8);                 \
        f32x4 acc_a[2], acc_b[2];                                                       \
        _Pragma("unroll")                                                               \
        for (int mt = 0; mt < 2; mt++) {            /* preact (f16->f32) as C-init */   \
            f16x4 av = ABUF[mt];                                                        \
            acc_a[mt] = f32x4{(float)av[0], (float)av[1], (float)av[2], (float)av[3]};  \
            acc_b[mt] = f32x4{0.f, 0.f, 0.f, 0.f};                                      \
        }                                                                               \
        const long t2 = (tt + 2 > 511) ? 511 : (tt + 2);                                \
        const _Float16* rp = abase + t2 * 65536;                                        \
        _Pragma("unroll")                                                               \
        for (int mt = 0; mt < 2; mt++) ABUF[mt] = *(const f16x4*)(rp + mt * 16);        \
        _Pragma("unroll")                                                               \
        for (int r = 0; r < 4; r++) {               /* 4 chains, depth 4 */             \
            _Pragma("unroll")                                                           \
            for (int mt = 0; mt < 2; mt++)                                              \
                acc_a[mt] = __builtin_amdgcn_mfma_f32_16x16x32_f16(                     \
                    whf[r][mt], hf[r], acc_a[mt], 0, 0, 0);                             \
            _Pragma("unroll")                                                           \
            for (int mt = 0; mt < 2; mt++)                                              \
                acc_b[mt] = __builtin_amdgcn_mfma_f32_16x16x32_f16(                     \
                    whf[r + 4][mt], hf[r + 4], acc_b[mt], 0, 0, 0);                     \
        }                                                                               \
        _Pragma("unroll")                                                               \
        for (int mt = 0; mt < 2; mt++) {                                                \
            f32x4 s = acc_a[mt] + acc_b[mt];                                            \
            float r0 = sigmoid_scaled(s[0]), r1 = sigmoid_scaled(s[1]);                 \
            float r2 = sigmoid_scaled(s[2]), r3 = sigmoid_scaled(s[3]);                 \
            union { fp16v2 h2[2]; f16x4 v4; } hp;                                       \
            hp.h2[0] = __builtin_amdgcn_cvt_pkrtz(r0, r1);                              \
            hp.h2[1] = __builtin_amdgcn_cvt_pkrtz(r2, r3);                              \
            *(f16x4*)(hw + ln * HSTR + wv * 32 + mt * 16 + q * 4) = hp.v4;              \
        }                                                                               \
        block_sync_lds();                                                               \
    }

    for (int t = 0; t < S_LEN; t += 2) {
        STEP(t, abuf0);
        STEP(t + 1, abuf1);
    }
#undef STEP

    const _Float16* hf0 = hbuf;   // step 511 (odd) wrote buffer 0

    {   // hidden -> out[256 + (b0+row)*256 + j], 8 f32 per thread
        const int row = tid >> 5, j0 = (tid & 31) * 8;
        float* dst = out + 256 + (long)(b0 + row) * HID + j0;
        f32x4 w0, w1;
#pragma unroll
        for (int r = 0; r < 4; r++) w0[r] = (float)hf0[row * HSTR + j0 + r];
#pragma unroll
        for (int r = 0; r < 4; r++) w1[r] = (float)hf0[row * HSTR + j0 + 4 + r];
        *(f32x4*)dst       = w0;
        *(f32x4*)(dst + 4) = w1;
    }

    {   // sig head: 32 partials x 8 elems per row
        const int row = tid >> 5, part = tid & 31;
        float s = 0.f;
#pragma unroll
        for (int jj = 0; jj < 8; jj++) {
            const int j = part * 8 + jj;
            s += (float)hf0[row * HSTR + j] * fcw[j];
        }
        red[row * 32 + part] = s;
    }
    __syncthreads();
    if (tid < 16) {
        float s = fcb[0];
#pragma unroll
        for (int p = 0; p < 32; p++) s += red[tid * 32 + p];
        s *= NLOG2E;
        out[b0 + tid] = sigmoid_scaled(s);
    }
}

extern "C" void kernel_launch(void* const* d_in, const int* in_sizes, int n_in,
                              void* d_out, int out_size, void* d_ws, size_t ws_size,
                              hipStream_t stream) {
    const int*   words = (const int*)d_in[0];
    const float* emb   = (const float*)d_in[1];
    const float* Wi    = (const float*)d_in[2];
    const float* Wh    = (const float*)d_in[3];
    const float* fcw   = (const float*)d_in[4];
    const float* fcb   = (const float*)d_in[5];
    _Float16* EW   = (_Float16*)d_ws;                          // 25.7 MB f16
    _Float16* As   = (_Float16*)((char*)d_ws + EW_BYTES);      // 64 MB f16
    float*    outp = (float*)d_out;
    // ws >= 118.5 MB proven in R7 (k_recur_s ran); need 92.8 MB here.

    hipLaunchKernelGGL(k_embwi,  dim3(NPROD), dim3(256), 0, stream, emb, Wi, EW);
    hipLaunchKernelGGL(k_expand, dim3(16384), dim3(256), 0, stream, words, EW, As);
    hipLaunchKernelGGL(k_recur,  dim3(BATCH / 16), dim3(512), 0, stream,
                       Wh, As, fcw, fcb, outp);
}

// Round 10
// 454.574 us; speedup vs baseline: 1.8882x; 1.1154x over previous
//
#include <hip/hip_runtime.h>

#define S_LEN 512
#define BATCH 256
#define EMB   300
#define HID   256
#define VOCAB 50257
#define NPROD 786
#define NLOG2E -1.44269504089f

#define EW_BYTES 25731584ull            // 50257*256*2 (f16, pre-scaled by -log2e)

typedef __attribute__((ext_vector_type(8))) _Float16 f16x8;
typedef __attribute__((ext_vector_type(4))) _Float16 f16x4;
typedef __attribute__((ext_vector_type(2))) __fp16   fp16v2;
typedef __attribute__((ext_vector_type(4))) float    f32x4;

// Barrier waiting only lgkmcnt(0): LDS ordered, global loads stay in flight.
__device__ __forceinline__ void block_sync_lds() {
    asm volatile("" ::: "memory");
    __builtin_amdgcn_s_waitcnt(0xC07F);   // vmcnt=63, expcnt=7, lgkmcnt=0
    __builtin_amdgcn_s_barrier();
    asm volatile("" ::: "memory");
}

__device__ __forceinline__ float sigmoid_scaled(float xs) {   // xs = -log2e * x
    float e = __builtin_amdgcn_exp2f(xs);
    return __builtin_amdgcn_rcpf(1.0f + e);
}

// ---------------------------------------------------------------------------
// Producer: EW[v][j] = f16( -log2e * (emb[v] @ Wi)[j] ). (unchanged from R9)
// ---------------------------------------------------------------------------
__global__ __launch_bounds__(256, 1)
void k_embwi(const float* __restrict__ emb, const float* __restrict__ Wi,
             _Float16* __restrict__ EW) {
    const int tid  = threadIdx.x;
    const int wv   = tid >> 6;
    const int lane = tid & 63;
    const int ln   = lane & 15;
    const int q    = lane >> 4;
    const int m0   = blockIdx.x * 64;

    f16x8 bfrag[10][4];
#pragma unroll
    for (int kc = 0; kc < 10; kc++) {
#pragma unroll
        for (int nt = 0; nt < 4; nt++) {
            const int n = wv * 64 + nt * 16 + ln;
            f16x8 u;
#pragma unroll
            for (int j = 0; j < 8; j++) {
                const int k = kc * 32 + q * 8 + j;
                u[j] = (k < EMB) ? (_Float16)(Wi[k * HID + n] * NLOG2E) : (_Float16)0.f;
            }
            bfrag[kc][nt] = u;
        }
    }

    const float* arow[4];
#pragma unroll
    for (int mt = 0; mt < 4; mt++) {
        int row = m0 + mt * 16 + ln; if (row >= VOCAB) row = VOCAB - 1;
        arow[mt] = emb + (long)row * EMB + q * 8;
    }

    auto load_af = [&](int kc, int mt) -> f16x8 {
        const float* p = arow[mt] + kc * 32;
        f16x8 v;
        if (kc < 9 || q == 0) {
            f32x4 a = *(const f32x4*)p;
            f32x4 b = *(const f32x4*)(p + 4);
#pragma unroll
            for (int r = 0; r < 4; r++) { v[r] = (_Float16)a[r]; v[4 + r] = (_Float16)b[r]; }
        } else if (q == 1) {
            f32x4 a = *(const f32x4*)p;
#pragma unroll
            for (int r = 0; r < 4; r++) { v[r] = (_Float16)a[r]; v[4 + r] = (_Float16)0.f; }
        } else {
#pragma unroll
            for (int r = 0; r < 8; r++) v[r] = (_Float16)0.f;
        }
        return v;
    };

    f32x4 acc[4][4];
#pragma unroll
    for (int mt = 0; mt < 4; mt++)
#pragma unroll
        for (int nt = 0; nt < 4; nt++)
            acc[mt][nt] = f32x4{0.f, 0.f, 0.f, 0.f};

    f16x8 af[4], afn[4];
#pragma unroll
    for (int mt = 0; mt < 4; mt++) af[mt] = load_af(0, mt);

#pragma unroll
    for (int kc = 0; kc < 10; kc++) {
        if (kc < 9) {
#pragma unroll
            for (int mt = 0; mt < 4; mt++) afn[mt] = load_af(kc + 1, mt);
        }
#pragma unroll
        for (int mt = 0; mt < 4; mt++)
#pragma unroll
            for (int nt = 0; nt < 4; nt++)
                acc[mt][nt] = __builtin_amdgcn_mfma_f32_16x16x32_f16(
                    af[mt], bfrag[kc][nt], acc[mt][nt], 0, 0, 0);
#pragma unroll
        for (int mt = 0; mt < 4; mt++) af[mt] = afn[mt];
    }

#pragma unroll
    for (int mt = 0; mt < 4; mt++)
#pragma unroll
        for (int nt = 0; nt < 4; nt++) {
            const int col = wv * 64 + nt * 16 + ln;
#pragma unroll
            for (int r = 0; r < 4; r++) {
                const int mm = m0 + mt * 16 + q * 4 + r;
                if (mm < VOCAB) EW[(long)mm * HID + col] = (_Float16)acc[mt][nt][r];
            }
        }
}

// ---------------------------------------------------------------------------
// Expand: A_seq[t][b][j] = EW[words[b,t]][j]. (unchanged from R9)
// ---------------------------------------------------------------------------
__global__ __launch_bounds__(256)
void k_expand(const int* __restrict__ words, const _Float16* __restrict__ EW,
              _Float16* __restrict__ As) {
    const int g  = blockIdx.x * 256 + threadIdx.x;
    const int e0 = g << 3;
    const int t  = e0 >> 16;
    const int b  = (e0 >> 8) & 255;
    const int j0 = e0 & 255;
    const _Float16* src = EW + ((long)words[b * S_LEN + t] << 8) + j0;
    *(f16x8*)(As + e0) = *(const f16x8*)src;
}

// ---------------------------------------------------------------------------
// Consumer: 32 blocks x 8 batch rows, 512 threads (8 waves, 2/SIMD).
// Halving rows/block doubles active CUs (16->32) and halves each CU's unique
// h traffic: MFMA n=16 is half-padded, lanes ln>=8 read DUPLICATE LDS
// addresses of ln-8 (same-address broadcast is free) so each ds_read_b128
// moves 512 B unique; h writes predicated to ln<8. Per-CU LDS pipe ~450
// cyc/step vs R9's ~1190 -> trans/VALU co-binding.
// ---------------------------------------------------------------------------
#define HSTR 264
#define HB8  (8 * HSTR)

__global__ __launch_bounds__(512, 2)
void k_recur(const float* __restrict__ Wh, const _Float16* __restrict__ As,
             const float* __restrict__ fcw, const float* __restrict__ fcb,
             float* __restrict__ out) {
    __shared__ __attribute__((aligned(16))) _Float16 hbuf[2 * HB8];
    __shared__ float red[512];

    const int tid  = threadIdx.x;
    const int wv   = tid >> 6;        // 0..7, j-slice of 32
    const int lane = tid & 63;
    const int ln   = lane & 15;
    const int lnn  = ln & 7;          // broadcast source row
    const int q    = lane >> 4;
    const int b0   = blockIdx.x * 8;

    // Wh^T frags (scaled by -log2e): A'[m=j][k], j = wv*32 + mt*16 + ln
    f16x8 whf[8][2];
#pragma unroll
    for (int kc = 0; kc < 8; kc++) {
#pragma unroll
        for (int mt = 0; mt < 2; mt++) {
            const int j = wv * 32 + mt * 16 + ln;
            f16x8 u;
#pragma unroll
            for (int jj = 0; jj < 8; jj++)
                u[jj] = (_Float16)(Wh[(kc * 32 + q * 8 + jj) * HID + j] * NLOG2E);
            whf[kc][mt] = u;
        }
    }

    for (int i = tid; i < 2 * HB8; i += 512) hbuf[i] = (_Float16)0.f;
    __syncthreads();

    const int jbase = wv * 32 + q * 4;   // + mt*16
    const _Float16* abase = As + (long)(b0 + lnn) * HID + jbase;
    f16x4 abuf0[2], abuf1[2];
#pragma unroll
    for (int mt = 0; mt < 2; mt++) abuf0[mt] = *(const f16x4*)(abase + 0L * 65536 + mt * 16);
#pragma unroll
    for (int mt = 0; mt < 2; mt++) abuf1[mt] = *(const f16x4*)(abase + 1L * 65536 + mt * 16);

#define STEP(T, ABUF)                                                                   \
    {                                                                                   \
        const int tt = (T);                                                             \
        const _Float16* hr = hbuf + ((tt & 1) ? HB8 : 0);                               \
        _Float16*       hw = hbuf + ((tt & 1) ? 0 : HB8);                               \
        f16x8 hf[8];                                                                    \
        _Pragma("unroll")                                                               \
        for (int kc = 0; kc < 8; kc++)                                                  \
            hf[kc] = *(const f16x8*)(hr + lnn * HSTR + kc * 32 + q * 8);                \
        f32x4 acc_a[2], acc_b[2];                                                       \
        _Pragma("unroll")                                                               \
        for (int mt = 0; mt < 2; mt++) {            /* preact (f16->f32) as C-init */   \
            f16x4 av = ABUF[mt];                                                        \
            acc_a[mt] = f32x4{(float)av[0], (float)av[1], (float)av[2], (float)av[3]};  \
            acc_b[mt] = f32x4{0.f, 0.f, 0.f, 0.f};                                      \
        }                                                                               \
        const long t2 = (tt + 2 > 511) ? 511 : (tt + 2);                                \
        const _Float16* rp = abase + t2 * 65536;                                        \
        _Pragma("unroll")                                                               \
        for (int mt = 0; mt < 2; mt++) ABUF[mt] = *(const f16x4*)(rp + mt * 16);        \
        _Pragma("unroll")                                                               \
        for (int r = 0; r < 4; r++) {               /* 4 chains, depth 4 */             \
            _Pragma("unroll")                                                           \
            for (int mt = 0; mt < 2; mt++)                                              \
                acc_a[mt] = __builtin_amdgcn_mfma_f32_16x16x32_f16(                     \
                    whf[r][mt], hf[r], acc_a[mt], 0, 0, 0);                             \
            _Pragma("unroll")                                                           \
            for (int mt = 0; mt < 2; mt++)                                              \
                acc_b[mt] = __builtin_amdgcn_mfma_f32_16x16x32_f16(                     \
                    whf[r + 4][mt], hf[r + 4], acc_b[mt], 0, 0, 0);                     \
        }                                                                               \
        _Pragma("unroll")                                                               \
        for (int mt = 0; mt < 2; mt++) {                                                \
            f32x4 s = acc_a[mt] + acc_b[mt];                                            \
            float r0 = sigmoid_scaled(s[0]), r1 = sigmoid_scaled(s[1]);                 \
            float r2 = sigmoid_scaled(s[2]), r3 = sigmoid_scaled(s[3]);                 \
            union { fp16v2 h2[2]; f16x4 v4; } hp;                                       \
            hp.h2[0] = __builtin_amdgcn_cvt_pkrtz(r0, r1);                              \
            hp.h2[1] = __builtin_amdgcn_cvt_pkrtz(r2, r3);                              \
            if (ln < 8)                                                                 \
                *(f16x4*)(hw + ln * HSTR + wv * 32 + mt * 16 + q * 4) = hp.v4;          \
        }                                                                               \
        block_sync_lds();                                                               \
    }

    for (int t = 0; t < S_LEN; t += 2) {
        STEP(t, abuf0);
        STEP(t + 1, abuf1);
    }
#undef STEP

    const _Float16* hf0 = hbuf;   // step 511 (odd) wrote buffer 0

    {   // hidden -> out[256 + (b0+row)*256 + j], rows 0..7, 4 f32 per thread
        const int row = tid >> 6, j0 = (tid & 63) * 4;
        float* dst = out + 256 + (long)(b0 + row) * HID + j0;
        f32x4 w;
#pragma unroll
        for (int r = 0; r < 4; r++) w[r] = (float)hf0[row * HSTR + j0 + r];
        *(f32x4*)dst = w;
    }

    {   // sig head: 64 partials x 4 elems per row
        const int row = tid >> 6, part = tid & 63;
        float s = 0.f;
#pragma unroll
        for (int jj = 0; jj < 4; jj++) {
            const int j = part * 4 + jj;
            s += (float)hf0[row * HSTR + j] * fcw[j];
        }
        red[row * 64 + part] = s;
    }
    __syncthreads();
    if (tid < 8) {
        float s = fcb[0];
#pragma unroll
        for (int p = 0; p < 64; p++) s += red[tid * 64 + p];
        s *= NLOG2E;
        out[b0 + tid] = sigmoid_scaled(s);
    }
}

extern "C" void kernel_launch(void* const* d_in, const int* in_sizes, int n_in,
                              void* d_out, int out_size, void* d_ws, size_t ws_size,
                              hipStream_t stream) {
    const int*   words = (const int*)d_in[0];
    const float* emb   = (const float*)d_in[1];
    const float* Wi    = (const float*)d_in[2];
    const float* Wh    = (const float*)d_in[3];
    const float* fcw   = (const float*)d_in[4];
    const float* fcb   = (const float*)d_in[5];
    _Float16* EW   = (_Float16*)d_ws;                          // 25.7 MB f16
    _Float16* As   = (_Float16*)((char*)d_ws + EW_BYTES);      // 64 MB f16
    float*    outp = (float*)d_out;

    hipLaunchKernelGGL(k_embwi,  dim3(NPROD), dim3(256), 0, stream, emb, Wi, EW);
    hipLaunchKernelGGL(k_expand, dim3(16384), dim3(256), 0, stream, words, EW, As);
    hipLaunchKernelGGL(k_recur,  dim3(BATCH / 8), dim3(512), 0, stream,
                       Wh, As, fcw, fcb, outp);
}